// Round 5
// baseline (3026.779 us; speedup 1.0000x reference)
//
#include <hip/hip_runtime.h>
#include <hip/hip_bf16.h>

#define D_MODEL 256
#define NHEAD 8
#define DH 32
#define NLAYERS 4
#define DFF 1024
#define CC 2
#define DATA_DIM 128
#define PP 16
#define TT 64
#define BB 4
#define LL 1024
#define NEGV -1000000.0f
#define GRID 512

typedef __bf16 bf16_t;
typedef __bf16 bf16x8 __attribute__((ext_vector_type(8)));
typedef __bf16 bf16x4 __attribute__((ext_vector_type(4)));
typedef float v4f __attribute__((ext_vector_type(4)));

__device__ __forceinline__ bool my_isnan(float v) {
    unsigned u = __float_as_uint(v);
    return (u & 0x7fffffffu) > 0x7f800000u;
}

__device__ __forceinline__ void gld16(bf16_t* l, const bf16_t* g) {
    __builtin_amdgcn_global_load_lds(
        (const __attribute__((address_space(1))) void*)g,
        (__attribute__((address_space(3))) void*)l, 16, 0, 0);
}

struct KParams {
    // inputs
    const float* img; const float* acq; const float* nan_token; const float* pad_embed;
    const float* emb_w; const float* emb_b; const float* spatial;
    const float* t_w1; const float* t_b1; const float* t_w2; const float* t_b2;
    const float* t_w3; const float* t_b3;
    const float* in_proj_w; const float* in_proj_b;
    const float* out_proj_w; const float* out_proj_b;
    const float* lin1_w; const float* lin1_b;
    const float* lin2_w; const float* lin2_b;
    const float* norm1_w; const float* norm1_b;
    const float* norm2_w; const float* norm2_b;
    const float* mean_w1; const float* mean_b1; const float* mean_w2; const float* mean_b2;
    const float* lv_w1; const float* lv_b1; const float* lv_w2; const float* lv_b2;
    // workspace
    float* temb; float* kmaskf; int* framepad; int* masked;
    bf16_t* zb; bf16_t* xpb; bf16_t* qkvb; bf16_t* VtG; bf16_t* attnb; bf16_t* ff1b;
    bf16_t* inb; bf16_t* outb; bf16_t* l1b; bf16_t* l2b; bf16_t* embwb;
    bf16_t* w1b; bf16_t* w2b; bf16_t* hb;
    unsigned* gbar;   // arrival counter (monotonic)
    unsigned* ggo;    // go flag (monotonic phase), separate cacheline
    // output
    float* outF;
};

// ---------------------------------------------------------------------------
// Manual grid barrier v2. Round-3's 47us/barrier bug: RELAXED poll was served
// from the spinner's stale per-XCD L2 until eviction. Fix: ACQUIRE poll every
// iteration (invalidates stale lines) + fetch_add(0) RMW fallback (always
// coherent) every 32 sleeps. Arrival: one RMW per block on gbar; last arriver
// release-publishes the phase to ggo (single writer, separate line).
// ---------------------------------------------------------------------------
__device__ __forceinline__ void gsync(unsigned* bar, unsigned* go, unsigned phase, int tid) {
    __syncthreads();
    if (tid == 0) {
        unsigned old = __hip_atomic_fetch_add(bar, 1u, __ATOMIC_ACQ_REL,
                                              __HIP_MEMORY_SCOPE_AGENT);
        if (old == phase * (unsigned)GRID - 1u) {
            __hip_atomic_store(go, phase, __ATOMIC_RELEASE, __HIP_MEMORY_SCOPE_AGENT);
        } else {
            int it = 0;
            while (true) {
                if (__hip_atomic_load(go, __ATOMIC_ACQUIRE,
                                      __HIP_MEMORY_SCOPE_AGENT) >= phase) break;
                __builtin_amdgcn_s_sleep(4);
                if ((++it & 31) == 0 &&
                    __hip_atomic_fetch_add(go, 0u, __ATOMIC_ACQ_REL,
                                           __HIP_MEMORY_SCOPE_AGENT) >= phase) break;
            }
        }
    }
    __syncthreads();
}

// ---------------------------------------------------------------------------
// Stage bodies (carve LDS views out of the shared union)
// ---------------------------------------------------------------------------

__device__ __forceinline__ void f2b_one(const KParams& P, int i) {
    const int n0 = NLAYERS * 768 * D_MODEL;
    const int n1 = NLAYERS * D_MODEL * D_MODEL;
    const int n2 = NLAYERS * DFF * D_MODEL;
    const int n3 = NLAYERS * D_MODEL * DFF;
    const int n4 = D_MODEL * DATA_DIM;
    const int n5 = DFF * D_MODEL;
    const int n6 = DFF * D_MODEL;
    const int n7 = DATA_DIM * DFF;
    const float* s; bf16_t* d;
    if (i < n0) { s = P.in_proj_w; d = P.inb; }
    else if ((i -= n0) < n1) { s = P.out_proj_w; d = P.outb; }
    else if ((i -= n1) < n2) { s = P.lin1_w; d = P.l1b; }
    else if ((i -= n2) < n3) { s = P.lin2_w; d = P.l2b; }
    else if ((i -= n3) < n4) { s = P.emb_w; d = P.embwb; }
    else if ((i -= n4) < n5) { s = P.mean_w1; d = P.w1b; }
    else if ((i -= n5) < n6) { s = P.lv_w1; d = P.w1b + n5; }
    else if ((i -= n6) < n7) { s = P.mean_w2; d = P.w2b; }
    else { i -= n7; s = P.lv_w2; d = P.w2b + n7; }
    float4 v = *(const float4*)(s + i);
    bf16x4 o = {(bf16_t)v.x, (bf16_t)v.y, (bf16_t)v.z, (bf16_t)v.w};
    *(bf16x4*)(d + i) = o;
}

__device__ __forceinline__ void prep_frame(const KParams& P, unsigned char* sm, int tid, int f) {
    float* h1 = (float*)sm;
    float* h2 = (float*)(sm + 256);
    int* sAll = (int*)(sm + 768);
    if (tid == 0) *sAll = 1;
    __syncthreads();
    const float* fr = P.img + (size_t)f * (CC * 32 * 32);
    bool allpad = true;
    #pragma unroll
    for (int i = 0; i < 8; ++i) {
        float v = fr[tid + i * 256];
        allpad = allpad && (v == -9999.0f);
    }
    if (!allpad) *sAll = 0;
    __syncthreads();
    if (tid == 0) P.framepad[f] = *sAll;

    float t_in = P.acq[f];
    if (my_isnan(t_in)) t_in = 0.0f;
    if (tid < 64) h1[tid] = fmaxf(P.t_w1[tid] * t_in + P.t_b1[tid], 0.0f);
    __syncthreads();
    if (tid < 128) {
        float a = P.t_b2[tid];
        #pragma unroll 8
        for (int j = 0; j < 64; ++j) a += P.t_w2[tid * 64 + j] * h1[j];
        h2[tid] = fmaxf(a, 0.0f);
    }
    __syncthreads();
    {
        float a = P.t_b3[tid];
        #pragma unroll 8
        for (int j = 0; j < 128; ++j) a += P.t_w3[tid * 128 + j] * h2[j];
        P.temb[(size_t)f * D_MODEL + tid] = a;
    }
}

__device__ __forceinline__ void patchify_pair(const KParams& P, unsigned char* sm, int tid, int pk) {
    int* wAll = (int*)sm;
    int token = pk * 2 + (tid >> 7);
    int dd = tid & 127;
    int l = token & 1023, b = token >> 10;
    int t = l >> 4, p = l & 15;
    int c = dd >> 6, pr = (dd >> 3) & 7, pc = dd & 7;
    int hh = (p >> 2) * 8 + pr, ww = (p & 3) * 8 + pc;
    float v = P.img[(((size_t)(b * TT + t) * CC + c) * 32 + hh) * 32 + ww];
    bool nanp = my_isnan(v);
    if (nanp) v = fminf(fmaxf(P.nan_token[c], -10.0f), 10.0f);
    v = fminf(fmaxf(v, -10.0f), 10.0f);
    P.xpb[(size_t)token * DATA_DIM + dd] = (bf16_t)v;

    unsigned long long bal = __ballot(nanp);
    if ((tid & 63) == 0) wAll[tid >> 6] = (bal == 0xFFFFFFFFFFFFFFFFull) ? 1 : 0;
    __syncthreads();
    if (tid < 2) {
        int tk = pk * 2 + tid;
        int allnan = wAll[tid * 2] & wAll[tid * 2 + 1];
        int fp = P.framepad[tk >> 4];
        P.masked[tk] = allnan | fp;
        P.kmaskf[tk] = fp ? NEGV : 0.0f;
    }
}

// Embed GEMM tile: BM=128, BN=64, K=128, dbuf + swizzle.
__device__ __forceinline__ void embed_tile(const KParams& P, unsigned char* sm, int tid,
                                           int n0, int m0) {
    bf16_t* XsB = (bf16_t*)sm;             // [2][8192]
    bf16_t* WsB = (bf16_t*)(sm + 32768);   // [2][4096]
    const bf16_t* X = P.xpb;
    const bf16_t* W = P.embwb;
    int wave = tid >> 6, lane = tid & 63;
    int quad = lane >> 4, l16 = lane & 15;
    const int K = DATA_DIM, N = D_MODEL;

    v4f acc[2][4];
    #pragma unroll
    for (int i = 0; i < 2; ++i)
        #pragma unroll
        for (int j = 0; j < 4; ++j) acc[i][j] = (v4f){0.f, 0.f, 0.f, 0.f};

    int sr = tid >> 3, ss = tid & 7;
    int gc = (ss ^ (sr & 7)) * 8;

#define ESTAGE(bufi, k0)                                                              \
    do {                                                                              \
        _Pragma("unroll")                                                             \
        for (int p = 0; p < 4; ++p) {                                                 \
            int r = sr + p * 32;                                                      \
            gld16(XsB + (bufi) * 8192 + r * 64 + ss * 8, X + (size_t)(m0 + r) * K + (k0) + gc); \
        }                                                                             \
        _Pragma("unroll")                                                             \
        for (int p = 0; p < 2; ++p) {                                                 \
            int r = sr + p * 32;                                                      \
            gld16(WsB + (bufi) * 4096 + r * 64 + ss * 8, W + (size_t)(n0 + r) * K + (k0) + gc); \
        }                                                                             \
    } while (0)

    ESTAGE(0, 0);
    __syncthreads();
    const int T = K / 64;   // 2
    int swl = l16 & 7;
    for (int t = 0; t < T; ++t) {
        int buf = t & 1;
        if (t + 1 < T) ESTAGE(buf ^ 1, (t + 1) * 64);
        const bf16_t* Xc = XsB + buf * 8192;
        const bf16_t* Wc = WsB + buf * 4096;
        int ra = wave * 32 + l16;
        #pragma unroll
        for (int h = 0; h < 2; ++h) {
            int g8 = ((h * 4 + quad) ^ swl) * 8;
            bf16x8 af0 = *(const bf16x8*)(Xc + ra * 64 + g8);
            bf16x8 af1 = *(const bf16x8*)(Xc + (ra + 16) * 64 + g8);
            #pragma unroll
            for (int nt = 0; nt < 4; ++nt) {
                bf16x8 bfr = *(const bf16x8*)(Wc + (nt * 16 + l16) * 64 + g8);
                acc[0][nt] = __builtin_amdgcn_mfma_f32_16x16x32_bf16(af0, bfr, acc[0][nt], 0, 0, 0);
                acc[1][nt] = __builtin_amdgcn_mfma_f32_16x16x32_bf16(af1, bfr, acc[1][nt], 0, 0, 0);
            }
        }
        __syncthreads();
    }
#undef ESTAGE

    #pragma unroll
    for (int mt = 0; mt < 2; ++mt)
        #pragma unroll
        for (int nt = 0; nt < 4; ++nt) {
            int col = n0 + nt * 16 + l16;
            #pragma unroll
            for (int reg = 0; reg < 4; ++reg) {
                int row = m0 + wave * 32 + mt * 16 + quad * 4 + reg;
                int frame = row >> 4, p = row & 15;
                float v;
                if (P.framepad[frame]) {
                    v = P.pad_embed[col];
                } else {
                    v = acc[mt][nt][reg] + P.emb_b[col] + P.spatial[p * N + col]
                      + P.temb[(size_t)frame * N + col];
                }
                P.zb[(size_t)row * N + col] = (bf16_t)v;
            }
        }
}

// BM=128, BN=64, BK=64 dbuf GEMM tile. MODE1: bf16 out (+relu). MODE2: qkv split.
template <int MODE, int RELU>
__device__ __forceinline__ void gemm128_tile(
    unsigned char* sm, int tid,
    const bf16_t* __restrict__ X, const bf16_t* __restrict__ W,
    const float* __restrict__ bias, bf16_t* __restrict__ Y,
    bf16_t* __restrict__ Vt, int N, int K, int m0, int n0) {
    bf16_t* XsB = (bf16_t*)sm;             // [2][8192]
    bf16_t* WsB = (bf16_t*)(sm + 32768);   // [2][4096]
    int wave = tid >> 6, lane = tid & 63;
    int quad = lane >> 4, l16 = lane & 15;

    v4f acc[2][4];
    #pragma unroll
    for (int i = 0; i < 2; ++i)
        #pragma unroll
        for (int j = 0; j < 4; ++j) acc[i][j] = (v4f){0.f, 0.f, 0.f, 0.f};

    int sr = tid >> 3, ss = tid & 7;
    int gc = (ss ^ (sr & 7)) * 8;

#define GSTAGE(bufi, k0)                                                              \
    do {                                                                              \
        _Pragma("unroll")                                                             \
        for (int p = 0; p < 4; ++p) {                                                 \
            int r = sr + p * 32;                                                      \
            gld16(XsB + (bufi) * 8192 + r * 64 + ss * 8, X + (size_t)(m0 + r) * K + (k0) + gc); \
        }                                                                             \
        _Pragma("unroll")                                                             \
        for (int p = 0; p < 2; ++p) {                                                 \
            int r = sr + p * 32;                                                      \
            gld16(WsB + (bufi) * 4096 + r * 64 + ss * 8, W + (size_t)(n0 + r) * K + (k0) + gc); \
        }                                                                             \
    } while (0)

    GSTAGE(0, 0);
    __syncthreads();
    const int T = K >> 6;
    int swl = l16 & 7;
    for (int t = 0; t < T; ++t) {
        int buf = t & 1;
        if (t + 1 < T) GSTAGE(buf ^ 1, (t + 1) * 64);
        const bf16_t* Xc = XsB + buf * 8192;
        const bf16_t* Wc = WsB + buf * 4096;
        int ra = wave * 32 + l16;
        #pragma unroll
        for (int h = 0; h < 2; ++h) {
            int g8 = ((h * 4 + quad) ^ swl) * 8;
            bf16x8 af0 = *(const bf16x8*)(Xc + ra * 64 + g8);
            bf16x8 af1 = *(const bf16x8*)(Xc + (ra + 16) * 64 + g8);
            #pragma unroll
            for (int nt = 0; nt < 4; ++nt) {
                bf16x8 bfr = *(const bf16x8*)(Wc + (nt * 16 + l16) * 64 + g8);
                acc[0][nt] = __builtin_amdgcn_mfma_f32_16x16x32_bf16(af0, bfr, acc[0][nt], 0, 0, 0);
                acc[1][nt] = __builtin_amdgcn_mfma_f32_16x16x32_bf16(af1, bfr, acc[1][nt], 0, 0, 0);
            }
        }
        __syncthreads();
    }
#undef GSTAGE

    if constexpr (MODE == 1) {
        #pragma unroll
        for (int mt = 0; mt < 2; ++mt)
            #pragma unroll
            for (int nt = 0; nt < 4; ++nt) {
                int col = n0 + nt * 16 + l16;
                float bv = bias[col];
                #pragma unroll
                for (int reg = 0; reg < 4; ++reg) {
                    int row = m0 + wave * 32 + mt * 16 + quad * 4 + reg;
                    float v = acc[mt][nt][reg] + bv;
                    if (RELU) v = fmaxf(v, 0.0f);
                    Y[(size_t)row * N + col] = (bf16_t)v;
                }
            }
    } else {  // MODE 2
        if (n0 < 512) {
            #pragma unroll
            for (int mt = 0; mt < 2; ++mt)
                #pragma unroll
                for (int nt = 0; nt < 4; ++nt) {
                    int col = n0 + nt * 16 + l16;
                    float bv = bias[col];
                    #pragma unroll
                    for (int reg = 0; reg < 4; ++reg) {
                        int row = m0 + wave * 32 + mt * 16 + quad * 4 + reg;
                        float v = acc[mt][nt][reg] + bv;
                        Y[(size_t)row * 768 + col] = (bf16_t)v;
                    }
                }
        } else {
            bf16_t* VT = XsB;  // 64*136 elems, aliases dead staging buffer
            #pragma unroll
            for (int mt = 0; mt < 2; ++mt)
                #pragma unroll
                for (int nt = 0; nt < 4; ++nt) {
                    int cl = nt * 16 + l16;
                    float bv = bias[n0 + cl];
                    #pragma unroll
                    for (int reg = 0; reg < 4; ++reg) {
                        int rl = wave * 32 + mt * 16 + quad * 4 + reg;
                        VT[cl * 136 + rl] = (bf16_t)(acc[mt][nt][reg] + bv);
                    }
                }
            __syncthreads();
            int b = m0 >> 10, l0m = m0 & 1023;
            int cl = tid >> 2;
            int rbase = (tid & 3) * 8;
            int cg2 = n0 + cl - 512;
            int h = cg2 >> 5, d = cg2 & 31;
            bf16_t* dst = Vt + (((size_t)(b * NHEAD + h)) * DH + d) * LL + l0m;
            #pragma unroll
            for (int u = 0; u < 4; ++u)
                *(uint4*)(dst + rbase + u * 32) = *(const uint4*)(VT + cl * 136 + rbase + u * 32);
        }
    }
}

// Row GEMM + residual + LN, in place. BM=64, BN=256 (full row), BK=64,
// single-buffered (LDS 40KB to fit the union). Epilogue math = round-4 verified.
__device__ __forceinline__ void rowln_tile(
    unsigned char* sm, int tid,
    const bf16_t* __restrict__ X, const bf16_t* __restrict__ W,
    const float* __restrict__ bias, const bf16_t* __restrict__ Zres,
    bf16_t* __restrict__ Y, const float* __restrict__ lnw,
    const float* __restrict__ lnb, int K, int m0) {
    bf16_t* Xs = (bf16_t*)sm;            // 64*64  = 8 KB
    bf16_t* Ws = (bf16_t*)(sm + 8192);   // 256*64 = 32 KB
    int wave = tid >> 6, lane = tid & 63;
    int quad = lane >> 4, l16 = lane & 15;

    v4f acc[16];
    #pragma unroll
    for (int j = 0; j < 16; ++j) acc[j] = (v4f){0.f, 0.f, 0.f, 0.f};

    int sr = tid >> 3, ss = tid & 7;
    int gc = (ss ^ (sr & 7)) * 8;
    int swl = l16 & 7;
    const int T = K >> 6;
    for (int t = 0; t < T; ++t) {
        int k0 = t * 64;
        #pragma unroll
        for (int p = 0; p < 2; ++p) {
            int r = sr + p * 32;
            gld16(Xs + r * 64 + ss * 8, X + (size_t)(m0 + r) * K + k0 + gc);
        }
        #pragma unroll
        for (int p = 0; p < 8; ++p) {
            int r = sr + p * 32;
            gld16(Ws + r * 64 + ss * 8, W + (size_t)r * K + k0 + gc);
        }
        __syncthreads();
        int ra = wave * 16 + l16;
        #pragma unroll
        for (int h = 0; h < 2; ++h) {
            int g8 = ((h * 4 + quad) ^ swl) * 8;
            bf16x8 af = *(const bf16x8*)(Xs + ra * 64 + g8);
            #pragma unroll
            for (int nt = 0; nt < 16; ++nt) {
                bf16x8 bfr = *(const bf16x8*)(Ws + (nt * 16 + l16) * 64 + g8);
                acc[nt] = __builtin_amdgcn_mfma_f32_16x16x32_bf16(af, bfr, acc[nt], 0, 0, 0);
            }
        }
        __syncthreads();
    }

    // epilogue: bias + residual, in-register row LN
    float wv[16], bvv[16];
    #pragma unroll
    for (int nt = 0; nt < 16; ++nt) {
        int col = nt * 16 + l16;
        float bv = bias[col];
        wv[nt] = lnw[col];
        bvv[nt] = lnb[col];
        #pragma unroll
        for (int reg = 0; reg < 4; ++reg) {
            int row = m0 + wave * 16 + quad * 4 + reg;
            acc[nt][reg] += bv + (float)Zres[(size_t)row * D_MODEL + col];
        }
    }
    #pragma unroll
    for (int reg = 0; reg < 4; ++reg) {
        float s = 0.0f;
        #pragma unroll
        for (int nt = 0; nt < 16; ++nt) s += acc[nt][reg];
        s += __shfl_xor(s, 1); s += __shfl_xor(s, 2);
        s += __shfl_xor(s, 4); s += __shfl_xor(s, 8);
        float mean = s * (1.0f / D_MODEL);
        float sq = 0.0f;
        #pragma unroll
        for (int nt = 0; nt < 16; ++nt) { float d = acc[nt][reg] - mean; sq += d * d; }
        sq += __shfl_xor(sq, 1); sq += __shfl_xor(sq, 2);
        sq += __shfl_xor(sq, 4); sq += __shfl_xor(sq, 8);
        float inv = 1.0f / sqrtf(sq * (1.0f / D_MODEL) + 1e-5f);
        int row = m0 + wave * 16 + quad * 4 + reg;
        #pragma unroll
        for (int nt = 0; nt < 16; ++nt) {
            int col = nt * 16 + l16;
            Y[(size_t)row * D_MODEL + col] =
                (bf16_t)((acc[nt][reg] - mean) * inv * wv[nt] + bvv[nt]);
        }
    }
}

// Flash attention tile (one 64-q block of one (b,h)).
__device__ __forceinline__ void attn_tile(
    unsigned char* sm, int tid, int bid,
    const bf16_t* __restrict__ qkvb, const bf16_t* __restrict__ Vt,
    const int* __restrict__ masked_rows, const float* __restrict__ kmaskf,
    bf16_t* __restrict__ Ob) {
    bf16_t* KsB = (bf16_t*)sm;              // [2][128*40]   20480 B
    bf16_t* VsB = (bf16_t*)(sm + 20480);    // [2][32*136]   17408 B
    float*  KmsB = (float*)(sm + 37888);    // [2][128]       1024 B
    bf16_t* PsB = (bf16_t*)(sm + 38912);    // [4][16*136]   17408 B -> 56320

    int wave = tid >> 6, lane = tid & 63;
    int quad = lane >> 4, l16 = lane & 15;
    int h = bid & 7, b = (bid >> 3) & 3, qt = bid >> 5;
    int q0 = qt * 64 + wave * 16;
    const float scale = 0.17677669529663687f;

    bf16x8 qf = *(const bf16x8*)(qkvb + ((size_t)(b * LL) + q0 + l16) * 768 + h * DH + quad * 8);

    int mq = masked_rows[b * LL + q0 + l16];
    int qg = q0 + l16;

    float lrun = 0.0f;
    v4f oacc[2];
    oacc[0] = (v4f){0.f, 0.f, 0.f, 0.f};
    oacc[1] = (v4f){0.f, 0.f, 0.f, 0.f};

    int kr = tid >> 1, kh = (tid & 1) * 16;
    int vd = tid >> 3, vs0 = (tid & 7) * 8;
    const bf16_t* Kbase = qkvb + (size_t)(b * LL) * 768 + 256 + h * DH;
    const bf16_t* Vbase = Vt + (((size_t)(b * NHEAD + h)) * DH) * LL;
    const float* kmbase = kmaskf + b * LL;

    uint4 ka, kb, va, vb;
    float kmg;
    #define LOADC(c)                                                            \
        do {                                                                    \
            int _k0 = (c) * 128;                                                \
            ka = *(const uint4*)(Kbase + (size_t)(_k0 + kr) * 768 + kh);        \
            kb = *(const uint4*)(Kbase + (size_t)(_k0 + kr) * 768 + kh + 8);    \
            va = *(const uint4*)(Vbase + (size_t)vd * LL + _k0 + vs0);          \
            vb = *(const uint4*)(Vbase + (size_t)vd * LL + _k0 + 64 + vs0);     \
            kmg = (tid < 128) ? kmbase[_k0 + tid] : 0.0f;                       \
        } while (0)
    #define WRITEBUF(buf)                                                       \
        do {                                                                    \
            *(uint4*)(KsB + (buf) * 5120 + kr * 40 + kh) = ka;                  \
            *(uint4*)(KsB + (buf) * 5120 + kr * 40 + kh + 8) = kb;              \
            *(uint4*)(VsB + (buf) * 4352 + vd * 136 + vs0) = va;                \
            *(uint4*)(VsB + (buf) * 4352 + vd * 136 + 64 + vs0) = vb;           \
            if (tid < 128) KmsB[(buf) * 128 + tid] = kmg;                       \
        } while (0)

    LOADC(0);
    WRITEBUF(0);
    LOADC(1);

    bf16_t* Pw = PsB + wave * 2176;
    for (int c = 0; c < 8; ++c) {
        __syncthreads();
        int cur = c & 1;
        if (c + 1 < 8) WRITEBUF(cur ^ 1);
        if (c + 2 < 8) LOADC(c + 2);

        int k0 = c * 128;
        const bf16_t* Kc = KsB + cur * 5120;
        const bf16_t* Vc = VsB + cur * 4352;
        const float* kmc = KmsB + cur * 128;

        v4f sf[8];
        #pragma unroll
        for (int nt = 0; nt < 8; ++nt) {
            bf16x8 kf = *(const bf16x8*)(Kc + (nt * 16 + l16) * 40 + quad * 8);
            v4f zf = (v4f){0.f, 0.f, 0.f, 0.f};
            sf[nt] = __builtin_amdgcn_mfma_f32_16x16x32_bf16(kf, qf, zf, 0, 0, 0);
        }

        #pragma unroll
        for (int nt = 0; nt < 8; ++nt) {
            int kbase_nt = k0 + nt * 16 + quad * 4;
            float4 kmv = *(const float4*)(kmc + nt * 16 + quad * 4);
            float pv[4];
            #pragma unroll
            for (int reg = 0; reg < 4; ++reg) {
                float km = (reg == 0) ? kmv.x : (reg == 1) ? kmv.y : (reg == 2) ? kmv.z : kmv.w;
                float v = sf[nt][reg] * scale + km;
                if (mq && (qg != kbase_nt + reg)) v += NEGV;
                float p = __expf(v);
                lrun += p;
                pv[reg] = p;
            }
            bf16x4 pp = {(bf16_t)pv[0], (bf16_t)pv[1], (bf16_t)pv[2], (bf16_t)pv[3]};
            *(bf16x4*)(Pw + l16 * 136 + nt * 16 + quad * 4) = pp;
        }

        #pragma unroll
        for (int kt = 0; kt < 4; ++kt) {
            bf16x8 pf = *(const bf16x8*)(Pw + l16 * 136 + kt * 32 + quad * 8);
            #pragma unroll
            for (int nt2 = 0; nt2 < 2; ++nt2) {
                bf16x8 vf = *(const bf16x8*)(Vc + (nt2 * 16 + l16) * 136 + kt * 32 + quad * 8);
                oacc[nt2] = __builtin_amdgcn_mfma_f32_16x16x32_bf16(pf, vf, oacc[nt2], 0, 0, 0);
            }
        }
    }
    #undef LOADC
    #undef WRITEBUF

    lrun += __shfl_xor(lrun, 16);
    lrun += __shfl_xor(lrun, 32);
    float lq[4];
    #pragma unroll
    for (int reg = 0; reg < 4; ++reg) lq[reg] = __shfl(lrun, quad * 4 + reg);

    #pragma unroll
    for (int nt2 = 0; nt2 < 2; ++nt2)
        #pragma unroll
        for (int reg = 0; reg < 4; ++reg) {
            size_t row = (size_t)(b * LL) + q0 + quad * 4 + reg;
            Ob[row * 256 + h * DH + nt2 * 16 + l16] = (bf16_t)(oacc[nt2][reg] / lq[reg]);
        }
}

// Head stage 1 tile (BM=64, BN=64, K=256 dbuf).
__device__ __forceinline__ void head_h_tile(const KParams& P, unsigned char* sm, int tid,
                                            int head, int n0) {
    bf16_t* XsB = (bf16_t*)sm;             // [2][4096]
    bf16_t* WsB = (bf16_t*)(sm + 16384);   // [2][4096]
    int wave = tid >> 6, lane = tid & 63;
    int quad = lane >> 4, l16 = lane & 15;
    const bf16_t* W1h = P.w1b + (size_t)head * DFF * D_MODEL;
    const float* B1f = head ? P.lv_b1 : P.mean_b1;
    bf16_t* hbh = P.hb + (size_t)head * 64 * DFF;

    v4f acc[4];
    #pragma unroll
    for (int j = 0; j < 4; ++j) acc[j] = (v4f){0.f, 0.f, 0.f, 0.f};

    int sr = tid >> 3, ss = tid & 7;
    int gc = (ss ^ (sr & 7)) * 8;

#define HSTAGE(bufi, k0)                                                              \
    do {                                                                              \
        _Pragma("unroll")                                                             \
        for (int p = 0; p < 2; ++p) {                                                 \
            int r = sr + p * 32;                                                      \
            const bf16_t* xr = P.zb + (size_t)((r >> 4) * LL + (TT - 1) * PP + (r & 15)) * D_MODEL; \
            gld16(XsB + (bufi) * 4096 + r * 64 + ss * 8, xr + (k0) + gc);             \
            gld16(WsB + (bufi) * 4096 + r * 64 + ss * 8, W1h + (size_t)(n0 + r) * D_MODEL + (k0) + gc); \
        }                                                                             \
    } while (0)

    HSTAGE(0, 0);
    __syncthreads();
    const int T = D_MODEL / 64;   // 4
    int swl = l16 & 7;
    for (int t = 0; t < T; ++t) {
        int buf = t & 1;
        if (t + 1 < T) HSTAGE(buf ^ 1, (t + 1) * 64);
        const bf16_t* Xc = XsB + buf * 4096;
        const bf16_t* Wc = WsB + buf * 4096;
        int ra = wave * 16 + l16;
        #pragma unroll
        for (int h = 0; h < 2; ++h) {
            int g8 = ((h * 4 + quad) ^ swl) * 8;
            bf16x8 af = *(const bf16x8*)(Xc + ra * 64 + g8);
            #pragma unroll
            for (int nt = 0; nt < 4; ++nt) {
                bf16x8 bfr = *(const bf16x8*)(Wc + (nt * 16 + l16) * 64 + g8);
                acc[nt] = __builtin_amdgcn_mfma_f32_16x16x32_bf16(af, bfr, acc[nt], 0, 0, 0);
            }
        }
        __syncthreads();
    }
#undef HSTAGE

    #pragma unroll
    for (int nt = 0; nt < 4; ++nt) {
        int col = n0 + nt * 16 + l16;
        float bv = B1f[col];
        #pragma unroll
        for (int reg = 0; reg < 4; ++reg) {
            int row = wave * 16 + quad * 4 + reg;
            hbh[(size_t)row * DFF + col] = (bf16_t)fmaxf(acc[nt][reg] + bv, 0.0f);
        }
    }
}

__device__ __forceinline__ void head_out_blk(const KParams& P, unsigned char* sm, int tid, int bid) {
    bf16_t* hrow = (bf16_t*)sm;   // DFF elems = 2 KB
    int head = bid >> 7, rr = (bid >> 1) & 63, half = bid & 1;
    int b = rr >> 4, p = rr & 15;

    if (tid < 128)
        *(uint4*)(hrow + tid * 8) =
            *(const uint4*)(P.hb + ((size_t)head * 64 + rr) * DFF + tid * 8);
    __syncthreads();

    int ol = tid >> 2, quarter = tid & 3;
    int o = half * 64 + ol;
    const bf16_t* wrow = P.w2b + ((size_t)head * DATA_DIM + o) * DFF + quarter * 256;
    const bf16_t* hseg = hrow + quarter * 256;
    float acc = 0.0f;
    #pragma unroll 8
    for (int j = 0; j < 32; ++j) {
        bf16x8 w = *(const bf16x8*)(wrow + j * 8);
        bf16x8 hv = *(const bf16x8*)(hseg + j * 8);
        #pragma unroll
        for (int e = 0; e < 8; ++e) acc += (float)w[e] * (float)hv[e];
    }
    acc += __shfl_xor(acc, 1);
    acc += __shfl_xor(acc, 2);
    if (quarter == 0) {
        const float* B2 = head ? P.lv_b2 : P.mean_b2;
        float hi = head ? 5.0f : 10.0f;
        float v = fminf(fmaxf(acc + B2[o], -10.0f), hi);
        int c = o >> 6;
        int pr = (o >> 3) & 7, pc = o & 7;
        int hh = (p >> 2) * 8 + pr, ww = (p & 3) * 8 + pc;
        P.outF[(size_t)head * 8192 + ((size_t)(b * CC + c)) * 1024 + hh * 32 + ww] = v;
    }
}

// ---------------------------------------------------------------------------
// Persistent kernel: stages separated by the v2 grid barrier.
// 512 blocks, 2/CU guaranteed (LDS 56320 B, launch_bounds(256,2)).
// ---------------------------------------------------------------------------
__global__ __launch_bounds__(256, 2) void fused_all(KParams P) {
    __shared__ __align__(16) unsigned char sm[56320];
    const int tid = threadIdx.x;
    const int bid = blockIdx.x;
    unsigned phase = 0;

    // ---- stage 1: weight f2b (grid-stride) + prep (blocks 0..255) ----
    {
        const int tot4 = (NLAYERS * 768 * D_MODEL + NLAYERS * D_MODEL * D_MODEL +
                          NLAYERS * DFF * D_MODEL + NLAYERS * D_MODEL * DFF +
                          D_MODEL * DATA_DIM + 2 * DFF * D_MODEL + 2 * DATA_DIM * DFF) / 4;
        for (int u = bid * 256 + tid; u < tot4; u += GRID * 256) f2b_one(P, u * 4);
        if (bid < BB * TT) prep_frame(P, sm, tid, bid);
    }
    gsync(P.gbar, P.ggo, ++phase, tid);

    // ---- stage 2: patchify (4 iterations of 512 blocks) ----
    for (int pk = bid; pk < (BB * LL) / 2; pk += GRID) {
        patchify_pair(P, sm, tid, pk);
        __syncthreads();
    }
    gsync(P.gbar, P.ggo, ++phase, tid);

    // ---- stage 3: embed GEMM (128 tiles) ----
    if (bid < 128) embed_tile(P, sm, tid, (bid & 3) * 64, (bid >> 2) * 128);
    gsync(P.gbar, P.ggo, ++phase, tid);

    // ---- transformer layers ----
    for (int l = 0; l < NLAYERS; ++l) {
        // qkv: 384 tiles (32 m x 12 n)
        if (bid < 384)
            gemm128_tile<2, 0>(sm, tid, P.zb, P.inb + (size_t)l * 768 * D_MODEL,
                               P.in_proj_b + (size_t)l * 768, P.qkvb, P.VtG,
                               768, D_MODEL, (bid / 12) * 128, (bid % 12) * 64);
        gsync(P.gbar, P.ggo, ++phase, tid);

        // attention: 512 tiles
        attn_tile(sm, tid, bid, P.qkvb, P.VtG, P.masked, P.kmaskf, P.attnb);
        gsync(P.gbar, P.ggo, ++phase, tid);

        // out_proj + residual + LN1 -> zb (in place): 64 tiles
        if (bid < 64)
            rowln_tile(sm, tid, P.attnb, P.outb + (size_t)l * D_MODEL * D_MODEL,
                       P.out_proj_b + (size_t)l * D_MODEL, P.zb, P.zb,
                       P.norm1_w + l * D_MODEL, P.norm1_b + l * D_MODEL,
                       D_MODEL, bid * 64);
        gsync(P.gbar, P.ggo, ++phase, tid);

        // ff1: 512 tiles (32 m x 16 n)
        gemm128_tile<1, 1>(sm, tid, P.zb, P.l1b + (size_t)l * DFF * D_MODEL,
                           P.lin1_b + (size_t)l * DFF, P.ff1b, nullptr,
                           DFF, D_MODEL, (bid >> 4) * 128, (bid & 15) * 64);
        gsync(P.gbar, P.ggo, ++phase, tid);

        // ff2 + residual + LN2 -> zb (in place): 64 tiles
        if (bid < 64)
            rowln_tile(sm, tid, P.ff1b, P.l2b + (size_t)l * D_MODEL * DFF,
                       P.lin2_b + (size_t)l * D_MODEL, P.zb, P.zb,
                       P.norm2_w + l * D_MODEL, P.norm2_b + l * D_MODEL,
                       DFF, bid * 64);
        gsync(P.gbar, P.ggo, ++phase, tid);
    }

    // ---- heads ----
    if (bid < 32) head_h_tile(P, sm, tid, bid >> 4, (bid & 15) * 64);
    gsync(P.gbar, P.ggo, ++phase, tid);
    if (bid < 256) head_out_blk(P, sm, tid, bid);
}

// ---------------------------------------------------------------------------
extern "C" void kernel_launch(void* const* d_in, const int* in_sizes, int n_in,
                              void* d_out, int out_size, void* d_ws, size_t ws_size,
                              hipStream_t stream) {
    const int M = BB * LL;   // 4096 tokens

    // ---- workspace carve-up ----
    char* wsb = (char*)d_ws;
    float* temb    = (float*)wsb;                    wsb += (size_t)BB * TT * D_MODEL * 4;
    float* kmaskf  = (float*)wsb;                    wsb += M * 4;
    int* framepad  = (int*)wsb;                      wsb += BB * TT * 4;
    int* masked    = (int*)wsb;                      wsb += M * 4;
    wsb = (char*)(((uintptr_t)wsb + 255) & ~(uintptr_t)255);
    bf16_t* zb     = (bf16_t*)wsb;                   wsb += (size_t)M * D_MODEL * 2;
    bf16_t* xpb    = (bf16_t*)wsb;                   wsb += (size_t)M * DATA_DIM * 2;
    bf16_t* qkvb   = (bf16_t*)wsb;                   wsb += (size_t)M * 768 * 2;
    bf16_t* VtG    = (bf16_t*)wsb;                   wsb += (size_t)M * D_MODEL * 2;
    bf16_t* attnb  = (bf16_t*)wsb;                   wsb += (size_t)M * D_MODEL * 2;
    bf16_t* ff1b   = (bf16_t*)wsb;                   wsb += (size_t)M * DFF * 2;
    bf16_t* inb    = (bf16_t*)wsb;                   wsb += (size_t)NLAYERS * 768 * D_MODEL * 2;
    bf16_t* outb   = (bf16_t*)wsb;                   wsb += (size_t)NLAYERS * D_MODEL * D_MODEL * 2;
    bf16_t* l1b    = (bf16_t*)wsb;                   wsb += (size_t)NLAYERS * DFF * D_MODEL * 2;
    bf16_t* l2b    = (bf16_t*)wsb;                   wsb += (size_t)NLAYERS * D_MODEL * DFF * 2;
    bf16_t* embwb  = (bf16_t*)wsb;                   wsb += (size_t)D_MODEL * DATA_DIM * 2;
    bf16_t* w1b    = (bf16_t*)wsb;                   wsb += (size_t)2 * DFF * D_MODEL * 2;
    bf16_t* w2b    = (bf16_t*)wsb;                   wsb += (size_t)2 * DATA_DIM * DFF * 2;
    bf16_t* hb     = (bf16_t*)wsb;                   wsb += (size_t)2 * 64 * DFF * 2;
    wsb = (char*)(((uintptr_t)wsb + 255) & ~(uintptr_t)255);
    unsigned* gbar = (unsigned*)wsb;                 wsb += 256;
    unsigned* ggo  = gbar + 32;   // byte offset 128: separate cacheline

    // zero the barrier counter + go flag (stream-ordered, graph-capturable)
    hipMemsetAsync((void*)gbar, 0, 256, stream);

    KParams prm;
    prm.img        = (const float*)d_in[0];
    prm.acq        = (const float*)d_in[1];
    prm.nan_token  = (const float*)d_in[2];
    prm.pad_embed  = (const float*)d_in[3];
    prm.emb_w      = (const float*)d_in[4];
    prm.emb_b      = (const float*)d_in[5];
    prm.spatial    = (const float*)d_in[6];
    prm.t_w1       = (const float*)d_in[7];
    prm.t_b1       = (const float*)d_in[8];
    prm.t_w2       = (const float*)d_in[9];
    prm.t_b2       = (const float*)d_in[10];
    prm.t_w3       = (const float*)d_in[11];
    prm.t_b3       = (const float*)d_in[12];
    prm.in_proj_w  = (const float*)d_in[13];
    prm.in_proj_b  = (const float*)d_in[14];
    prm.out_proj_w = (const float*)d_in[15];
    prm.out_proj_b = (const float*)d_in[16];
    prm.lin1_w     = (const float*)d_in[17];
    prm.lin1_b     = (const float*)d_in[18];
    prm.lin2_w     = (const float*)d_in[19];
    prm.lin2_b     = (const float*)d_in[20];
    prm.norm1_w    = (const float*)d_in[21];
    prm.norm1_b    = (const float*)d_in[22];
    prm.norm2_w    = (const float*)d_in[23];
    prm.norm2_b    = (const float*)d_in[24];
    prm.mean_w1    = (const float*)d_in[25];
    prm.mean_b1    = (const float*)d_in[26];
    prm.mean_w2    = (const float*)d_in[27];
    prm.mean_b2    = (const float*)d_in[28];
    prm.lv_w1      = (const float*)d_in[29];
    prm.lv_b1      = (const float*)d_in[30];
    prm.lv_w2      = (const float*)d_in[31];
    prm.lv_b2      = (const float*)d_in[32];
    prm.temb = temb; prm.kmaskf = kmaskf; prm.framepad = framepad; prm.masked = masked;
    prm.zb = zb; prm.xpb = xpb; prm.qkvb = qkvb; prm.VtG = VtG;
    prm.attnb = attnb; prm.ff1b = ff1b;
    prm.inb = inb; prm.outb = outb; prm.l1b = l1b; prm.l2b = l2b; prm.embwb = embwb;
    prm.w1b = w1b; prm.w2b = w2b; prm.hb = hb;
    prm.gbar = gbar; prm.ggo = ggo;
    prm.outF = (float*)d_out;

    fused_all<<<dim3(GRID), dim3(256), 0, stream>>>(prm);
}

// Round 7
// 389.042 us; speedup vs baseline: 7.7801x; 7.7801x over previous
//
#include <hip/hip_runtime.h>
#include <hip/hip_bf16.h>

#define D_MODEL 256
#define NHEAD 8
#define DH 32
#define NLAYERS 4
#define DFF 1024
#define CC 2
#define DATA_DIM 128
#define PP 16
#define TT 64
#define BB 4
#define LL 1024
#define NEGV -1000000.0f

typedef __bf16 bf16_t;
typedef __bf16 bf16x8 __attribute__((ext_vector_type(8)));
typedef __bf16 bf16x4 __attribute__((ext_vector_type(4)));
typedef float v4f __attribute__((ext_vector_type(4)));

__device__ __forceinline__ bool my_isnan(float v) {
    unsigned u = __float_as_uint(v);
    return (u & 0x7fffffffu) > 0x7f800000u;
}

__device__ __forceinline__ void gld16(bf16_t* l, const bf16_t* g) {
    __builtin_amdgcn_global_load_lds(
        (const __attribute__((address_space(1))) void*)g,
        (__attribute__((address_space(3))) void*)l, 16, 0, 0);
}

// ---------------------------------------------------------------------------
// Merged: fp32->bf16 weight conversion (grid-stride) + prep (blocks 0..255).
// (Verified in round 4.)
// ---------------------------------------------------------------------------
__global__ __launch_bounds__(256) void f2b_prep_kernel(
    const float* __restrict__ in_proj_w, bf16_t* __restrict__ inb,
    const float* __restrict__ out_proj_w, bf16_t* __restrict__ outb,
    const float* __restrict__ lin1_w, bf16_t* __restrict__ l1b,
    const float* __restrict__ lin2_w, bf16_t* __restrict__ l2b,
    const float* __restrict__ emb_w, bf16_t* __restrict__ embwb,
    const float* __restrict__ mean_w1, const float* __restrict__ lv_w1, bf16_t* __restrict__ w1b,
    const float* __restrict__ mean_w2, const float* __restrict__ lv_w2, bf16_t* __restrict__ w2b,
    const float* __restrict__ img, const float* __restrict__ acq,
    const float* __restrict__ t_w1, const float* __restrict__ t_b1,
    const float* __restrict__ t_w2, const float* __restrict__ t_b2,
    const float* __restrict__ t_w3, const float* __restrict__ t_b3,
    float* __restrict__ temb, int* __restrict__ framepad) {
    const int n0 = NLAYERS * 768 * D_MODEL;
    const int n1 = NLAYERS * D_MODEL * D_MODEL;
    const int n2 = NLAYERS * DFF * D_MODEL;
    const int n3 = NLAYERS * D_MODEL * DFF;
    const int n4 = D_MODEL * DATA_DIM;
    const int n5 = DFF * D_MODEL;
    const int n6 = DFF * D_MODEL;
    const int n7 = DATA_DIM * DFF;
    const int n8 = DATA_DIM * DFF;
    int tid = threadIdx.x;
    int i = (blockIdx.x * 256 + tid) * 4;
    const float* s = nullptr; bf16_t* d = nullptr;
    if (i < n0) { s = in_proj_w; d = inb; }
    else if ((i -= n0) < n1) { s = out_proj_w; d = outb; }
    else if ((i -= n1) < n2) { s = lin1_w; d = l1b; }
    else if ((i -= n2) < n3) { s = lin2_w; d = l2b; }
    else if ((i -= n3) < n4) { s = emb_w; d = embwb; }
    else if ((i -= n4) < n5) { s = mean_w1; d = w1b; }
    else if ((i -= n5) < n6) { s = lv_w1; d = w1b + n5; }
    else if ((i -= n6) < n7) { s = mean_w2; d = w2b; }
    else if ((i -= n7) < n8) { s = lv_w2; d = w2b + n7; }
    if (s) {
        float4 v = *(const float4*)(s + i);
        bf16x4 o = {(bf16_t)v.x, (bf16_t)v.y, (bf16_t)v.z, (bf16_t)v.w};
        *(bf16x4*)(d + i) = o;
    }

    if (blockIdx.x >= BB * TT) return;
    int f = blockIdx.x;
    __shared__ float h1[64];
    __shared__ float h2[128];
    __shared__ int sAll;
    if (tid == 0) sAll = 1;
    __syncthreads();
    const float* fr = img + (size_t)f * (CC * 32 * 32);
    bool allpad = true;
    #pragma unroll
    for (int k = 0; k < 8; ++k) {
        float v = fr[tid + k * 256];
        allpad = allpad && (v == -9999.0f);
    }
    if (!allpad) sAll = 0;
    __syncthreads();
    if (tid == 0) framepad[f] = sAll;

    float t_in = acq[f];
    if (my_isnan(t_in)) t_in = 0.0f;
    if (tid < 64) h1[tid] = fmaxf(t_w1[tid] * t_in + t_b1[tid], 0.0f);
    __syncthreads();
    if (tid < 128) {
        float a = t_b2[tid];
        #pragma unroll 8
        for (int j = 0; j < 64; ++j) a += t_w2[tid * 64 + j] * h1[j];
        h2[tid] = fmaxf(a, 0.0f);
    }
    __syncthreads();
    {
        float a = t_b3[tid];
        #pragma unroll 8
        for (int j = 0; j < 128; ++j) a += t_w3[tid * 128 + j] * h2[j];
        temb[(size_t)f * D_MODEL + tid] = a;
    }
}

// ---------------------------------------------------------------------------
// Patchify: img -> xpb (bf16 4096x128), masked_rows, kmaskf. (R1 verified.)
// ---------------------------------------------------------------------------
__global__ __launch_bounds__(256) void patchify_kernel(
    const float* __restrict__ img, const float* __restrict__ nan_token,
    const int* __restrict__ framepad,
    bf16_t* __restrict__ xpb, int* __restrict__ masked_rows,
    float* __restrict__ kmaskf) {
    int tid = threadIdx.x;
    int token = blockIdx.x * 2 + (tid >> 7);
    int dd = tid & 127;
    int l = token & 1023, b = token >> 10;
    int t = l >> 4, p = l & 15;
    int c = dd >> 6, pr = (dd >> 3) & 7, pc = dd & 7;
    int hh = (p >> 2) * 8 + pr, ww = (p & 3) * 8 + pc;
    float v = img[(((size_t)(b * TT + t) * CC + c) * 32 + hh) * 32 + ww];
    bool nanp = my_isnan(v);
    if (nanp) v = fminf(fmaxf(nan_token[c], -10.0f), 10.0f);
    v = fminf(fmaxf(v, -10.0f), 10.0f);
    xpb[(size_t)token * DATA_DIM + dd] = (bf16_t)v;

    __shared__ int wAll[4];
    unsigned long long bal = __ballot(nanp);
    if ((tid & 63) == 0) wAll[tid >> 6] = (bal == 0xFFFFFFFFFFFFFFFFull) ? 1 : 0;
    __syncthreads();
    if (tid < 2) {
        int tk = blockIdx.x * 2 + tid;
        int allnan = wAll[tid * 2] & wAll[tid * 2 + 1];
        int fp = framepad[tk >> 4];
        masked_rows[tk] = allnan | fp;
        kmaskf[tk] = fp ? NEGV : 0.0f;
    }
}

// ---------------------------------------------------------------------------
// Embed GEMM (R1 verified, 2-buffer; K=128 so only 2 steps).
// ---------------------------------------------------------------------------
__global__ __launch_bounds__(256) void embed_gemm(
    const bf16_t* __restrict__ X, const bf16_t* __restrict__ W,
    const float* __restrict__ emb_b, const float* __restrict__ spatial,
    const float* __restrict__ temb, const float* __restrict__ pad_embed,
    const int* __restrict__ framepad,
    bf16_t* __restrict__ zb) {
    __shared__ __align__(16) bf16_t Xs[2][128 * 64];
    __shared__ __align__(16) bf16_t Ws[2][64 * 64];
    int tid = threadIdx.x;
    int wave = tid >> 6, lane = tid & 63;
    int quad = lane >> 4, l16 = lane & 15;
    int m0 = blockIdx.y * 128, n0 = blockIdx.x * 64;
    const int K = DATA_DIM, N = D_MODEL;

    v4f acc[2][4];
    #pragma unroll
    for (int i = 0; i < 2; ++i)
        #pragma unroll
        for (int j = 0; j < 4; ++j) acc[i][j] = (v4f){0.f, 0.f, 0.f, 0.f};

    int sr = tid >> 3, ss = tid & 7;
    int gc = (ss ^ (sr & 7)) * 8;

#define ESTAGE(bufi, k0)                                                          \
    do {                                                                          \
        _Pragma("unroll")                                                         \
        for (int p = 0; p < 4; ++p) {                                             \
            int r = sr + p * 32;                                                  \
            gld16(Xs[bufi] + r * 64 + ss * 8, X + (size_t)(m0 + r) * K + (k0) + gc); \
        }                                                                         \
        _Pragma("unroll")                                                         \
        for (int p = 0; p < 2; ++p) {                                             \
            int r = sr + p * 32;                                                  \
            gld16(Ws[bufi] + r * 64 + ss * 8, W + (size_t)(n0 + r) * K + (k0) + gc); \
        }                                                                         \
    } while (0)

    ESTAGE(0, 0);
    __syncthreads();
    const int T = K / 64;   // 2
    int swl = l16 & 7;
    for (int t = 0; t < T; ++t) {
        int buf = t & 1;
        if (t + 1 < T) ESTAGE(buf ^ 1, (t + 1) * 64);
        const bf16_t* Xc = Xs[buf];
        const bf16_t* Wc = Ws[buf];
        int ra = wave * 32 + l16;
        #pragma unroll
        for (int h = 0; h < 2; ++h) {
            int g8 = ((h * 4 + quad) ^ swl) * 8;
            bf16x8 af0 = *(const bf16x8*)(Xc + ra * 64 + g8);
            bf16x8 af1 = *(const bf16x8*)(Xc + (ra + 16) * 64 + g8);
            #pragma unroll
            for (int nt = 0; nt < 4; ++nt) {
                bf16x8 bfr = *(const bf16x8*)(Wc + (nt * 16 + l16) * 64 + g8);
                acc[0][nt] = __builtin_amdgcn_mfma_f32_16x16x32_bf16(af0, bfr, acc[0][nt], 0, 0, 0);
                acc[1][nt] = __builtin_amdgcn_mfma_f32_16x16x32_bf16(af1, bfr, acc[1][nt], 0, 0, 0);
            }
        }
        __syncthreads();
    }
#undef ESTAGE

    #pragma unroll
    for (int mt = 0; mt < 2; ++mt)
        #pragma unroll
        for (int nt = 0; nt < 4; ++nt) {
            int col = n0 + nt * 16 + l16;
            #pragma unroll
            for (int reg = 0; reg < 4; ++reg) {
                int row = m0 + wave * 32 + mt * 16 + quad * 4 + reg;
                int frame = row >> 4, p = row & 15;
                float v;
                if (framepad[frame]) {
                    v = pad_embed[col];
                } else {
                    v = acc[mt][nt][reg] + emb_b[col] + spatial[p * N + col]
                      + temb[(size_t)frame * N + col];
                }
                zb[(size_t)row * N + col] = (bf16_t)v;
            }
        }
}

// ---------------------------------------------------------------------------
// MFMA GEMM: BM=128, BN=64, BK=64. 3-buffer ring, 2-tiles-ahead prefetch,
// counted vmcnt + raw s_barrier (loads stay in flight across barriers).
// Per-wave stage = 6 gld16. Wait order: vmcnt(N) BEFORE barrier -> all waves'
// tile-t LDS writes visible after barrier. WAR on ring protected by the
// top-of-step barrier (stage target (t+2)%3 was last read at step t-1).
// ---------------------------------------------------------------------------
template <int MODE, int RELU>
__global__ __launch_bounds__(256) void gemm_mfma(
    const bf16_t* __restrict__ X, const bf16_t* __restrict__ W,
    const float* __restrict__ bias, bf16_t* __restrict__ Y,
    bf16_t* __restrict__ Vt, int M, int N, int K) {
    __shared__ __align__(16) bf16_t Xs[3][128 * 64];   // 48 KB
    __shared__ __align__(16) bf16_t Ws[3][64 * 64];    // 24 KB
    int tid = threadIdx.x;
    int wave = tid >> 6, lane = tid & 63;
    int quad = lane >> 4, l16 = lane & 15;
    int m0 = blockIdx.y * 128, n0 = blockIdx.x * 64;

    v4f acc[2][4];
    #pragma unroll
    for (int i = 0; i < 2; ++i)
        #pragma unroll
        for (int j = 0; j < 4; ++j) acc[i][j] = (v4f){0.f, 0.f, 0.f, 0.f};

    int sr = tid >> 3, ss = tid & 7;
    int gc = (ss ^ (sr & 7)) * 8;

#define GSTAGE(bufi, k0)                                                          \
    do {                                                                          \
        _Pragma("unroll")                                                         \
        for (int p = 0; p < 4; ++p) {                                             \
            int r = sr + p * 32;                                                  \
            gld16(Xs[bufi] + r * 64 + ss * 8, X + (size_t)(m0 + r) * K + (k0) + gc); \
        }                                                                         \
        _Pragma("unroll")                                                         \
        for (int p = 0; p < 2; ++p) {                                             \
            int r = sr + p * 32;                                                  \
            gld16(Ws[bufi] + r * 64 + ss * 8, W + (size_t)(n0 + r) * K + (k0) + gc); \
        }                                                                         \
    } while (0)

    const int T = K >> 6;
    GSTAGE(0, 0);
    if (T > 1) GSTAGE(1, 64);
    int swl = l16 & 7;
    for (int t = 0; t < T; ++t) {
        int buf = t % 3;
        if (t + 1 < T) asm volatile("s_waitcnt vmcnt(6)" ::: "memory");
        else           asm volatile("s_waitcnt vmcnt(0)" ::: "memory");
        __builtin_amdgcn_s_barrier();
        __builtin_amdgcn_sched_barrier(0);
        if (t + 2 < T) GSTAGE((t + 2) % 3, (t + 2) * 64);
        const bf16_t* Xc = Xs[buf];
        const bf16_t* Wc = Ws[buf];
        int ra = wave * 32 + l16;
        #pragma unroll
        for (int h = 0; h < 2; ++h) {
            int g8 = ((h * 4 + quad) ^ swl) * 8;
            bf16x8 af0 = *(const bf16x8*)(Xc + ra * 64 + g8);
            bf16x8 af1 = *(const bf16x8*)(Xc + (ra + 16) * 64 + g8);
            #pragma unroll
            for (int nt = 0; nt < 4; ++nt) {
                bf16x8 bfr = *(const bf16x8*)(Wc + (nt * 16 + l16) * 64 + g8);
                acc[0][nt] = __builtin_amdgcn_mfma_f32_16x16x32_bf16(af0, bfr, acc[0][nt], 0, 0, 0);
                acc[1][nt] = __builtin_amdgcn_mfma_f32_16x16x32_bf16(af1, bfr, acc[1][nt], 0, 0, 0);
            }
        }
    }
#undef GSTAGE
    __syncthreads();   // all LDS reads done before any epilogue LDS reuse

    if constexpr (MODE == 1) {
        #pragma unroll
        for (int mt = 0; mt < 2; ++mt)
            #pragma unroll
            for (int nt = 0; nt < 4; ++nt) {
                int col = n0 + nt * 16 + l16;
                float bv = bias[col];
                #pragma unroll
                for (int reg = 0; reg < 4; ++reg) {
                    int row = m0 + wave * 32 + mt * 16 + quad * 4 + reg;
                    float v = acc[mt][nt][reg] + bv;
                    if (RELU) v = fmaxf(v, 0.0f);
                    Y[(size_t)row * N + col] = (bf16_t)v;
                }
            }
    } else {  // MODE 2
        if (n0 < 512) {
            #pragma unroll
            for (int mt = 0; mt < 2; ++mt)
                #pragma unroll
                for (int nt = 0; nt < 4; ++nt) {
                    int col = n0 + nt * 16 + l16;
                    float bv = bias[col];
                    #pragma unroll
                    for (int reg = 0; reg < 4; ++reg) {
                        int row = m0 + wave * 32 + mt * 16 + quad * 4 + reg;
                        float v = acc[mt][nt][reg] + bv;
                        Y[(size_t)row * 768 + col] = (bf16_t)v;
                    }
                }
        } else {
            // VT (64x136 = 8704 elems) aliases dead staging buffers (24576 avail).
            bf16_t* VT = &Xs[0][0];
            #pragma unroll
            for (int mt = 0; mt < 2; ++mt)
                #pragma unroll
                for (int nt = 0; nt < 4; ++nt) {
                    int cl = nt * 16 + l16;
                    float bv = bias[n0 + cl];
                    #pragma unroll
                    for (int reg = 0; reg < 4; ++reg) {
                        int rl = wave * 32 + mt * 16 + quad * 4 + reg;
                        VT[cl * 136 + rl] = (bf16_t)(acc[mt][nt][reg] + bv);
                    }
                }
            __syncthreads();
            int b = m0 >> 10, l0m = m0 & 1023;
            int cl = tid >> 2;
            int rbase = (tid & 3) * 8;
            int cg2 = n0 + cl - 512;
            int h = cg2 >> 5, d = cg2 & 31;
            bf16_t* dst = Vt + (((size_t)(b * NHEAD + h)) * DH + d) * LL + l0m;
            #pragma unroll
            for (int u = 0; u < 4; ++u)
                *(uint4*)(dst + rbase + u * 32) = *(const uint4*)(VT + cl * 136 + rbase + u * 32);
        }
    }
}

// ---------------------------------------------------------------------------
// Small-N MFMA GEMM + residual. 3-buffer ring + counted vmcnt.
// Per-wave stage = 4 gld16.
// ---------------------------------------------------------------------------
__global__ __launch_bounds__(256) void gemm_small(
    const bf16_t* __restrict__ X, const bf16_t* __restrict__ W,
    const float* __restrict__ bias, const bf16_t* __restrict__ Zres,
    bf16_t* __restrict__ Y, int M, int N, int K) {
    __shared__ __align__(16) bf16_t Xs[3][64 * 64];
    __shared__ __align__(16) bf16_t Ws[3][64 * 64];
    int tid = threadIdx.x;
    int wave = tid >> 6, lane = tid & 63;
    int quad = lane >> 4, l16 = lane & 15;
    int m0 = blockIdx.y * 64, n0 = blockIdx.x * 64;

    v4f acc[4];
    #pragma unroll
    for (int j = 0; j < 4; ++j) acc[j] = (v4f){0.f, 0.f, 0.f, 0.f};

    int sr = tid >> 3, ss = tid & 7;
    int gc = (ss ^ (sr & 7)) * 8;

#define SSTAGE(bufi, k0)                                                          \
    do {                                                                          \
        _Pragma("unroll")                                                         \
        for (int p = 0; p < 2; ++p) {                                             \
            int r = sr + p * 32;                                                  \
            gld16(Xs[bufi] + r * 64 + ss * 8, X + (size_t)(m0 + r) * K + (k0) + gc); \
            gld16(Ws[bufi] + r * 64 + ss * 8, W + (size_t)(n0 + r) * K + (k0) + gc); \
        }                                                                         \
    } while (0)

    const int T = K >> 6;
    SSTAGE(0, 0);
    if (T > 1) SSTAGE(1, 64);
    int swl = l16 & 7;
    for (int t = 0; t < T; ++t) {
        int buf = t % 3;
        if (t + 1 < T) asm volatile("s_waitcnt vmcnt(4)" ::: "memory");
        else           asm volatile("s_waitcnt vmcnt(0)" ::: "memory");
        __builtin_amdgcn_s_barrier();
        __builtin_amdgcn_sched_barrier(0);
        if (t + 2 < T) SSTAGE((t + 2) % 3, (t + 2) * 64);
        const bf16_t* Xc = Xs[buf];
        const bf16_t* Wc = Ws[buf];
        int ra = wave * 16 + l16;
        #pragma unroll
        for (int h = 0; h < 2; ++h) {
            int g8 = ((h * 4 + quad) ^ swl) * 8;
            bf16x8 af = *(const bf16x8*)(Xc + ra * 64 + g8);
            #pragma unroll
            for (int nt = 0; nt < 4; ++nt) {
                bf16x8 bfr = *(const bf16x8*)(Wc + (nt * 16 + l16) * 64 + g8);
                acc[nt] = __builtin_amdgcn_mfma_f32_16x16x32_bf16(af, bfr, acc[nt], 0, 0, 0);
            }
        }
    }
#undef SSTAGE

    #pragma unroll
    for (int nt = 0; nt < 4; ++nt) {
        int col = n0 + nt * 16 + l16;
        float bv = bias[col];
        #pragma unroll
        for (int reg = 0; reg < 4; ++reg) {
            int row = m0 + wave * 16 + quad * 4 + reg;
            float r = acc[nt][reg] + bv + (float)Zres[(size_t)row * N + col];
            Y[(size_t)row * N + col] = (bf16_t)r;
        }
    }
}

// ---------------------------------------------------------------------------
// Flash attention, bf16 MFMA (R1 verified, unchanged).
// ---------------------------------------------------------------------------
__global__ __launch_bounds__(256) void attn_mfma(
    const bf16_t* __restrict__ qkvb, const bf16_t* __restrict__ Vt,
    const int* __restrict__ masked_rows, const float* __restrict__ kmaskf,
    bf16_t* __restrict__ Ob) {
    __shared__ __align__(16) bf16_t Ks[2][128 * 40];
    __shared__ __align__(16) bf16_t Vs[2][32 * 136];
    __shared__ __align__(16) float  Kms[2][128];
    __shared__ __align__(16) bf16_t Ps[4][16 * 136];

    int tid = threadIdx.x;
    int wave = tid >> 6, lane = tid & 63;
    int quad = lane >> 4, l16 = lane & 15;
    int bid = blockIdx.x;
    int h = bid & 7, b = (bid >> 3) & 3, qt = bid >> 5;
    int q0 = qt * 64 + wave * 16;
    const float scale = 0.17677669529663687f;

    bf16x8 qf = *(const bf16x8*)(qkvb + ((size_t)(b * LL) + q0 + l16) * 768 + h * DH + quad * 8);

    int mq = masked_rows[b * LL + q0 + l16];
    int qg = q0 + l16;

    float lrun = 0.0f;
    v4f oacc[2];
    oacc[0] = (v4f){0.f, 0.f, 0.f, 0.f};
    oacc[1] = (v4f){0.f, 0.f, 0.f, 0.f};

    int kr = tid >> 1, kh = (tid & 1) * 16;
    int vd = tid >> 3, vs0 = (tid & 7) * 8;
    const bf16_t* Kbase = qkvb + (size_t)(b * LL) * 768 + 256 + h * DH;
    const bf16_t* Vbase = Vt + (((size_t)(b * NHEAD + h)) * DH) * LL;
    const float* kmbase = kmaskf + b * LL;

    uint4 ka, kb, va, vb;
    float kmg;
    #define LOADC(c)                                                            \
        do {                                                                    \
            int _k0 = (c) * 128;                                                \
            ka = *(const uint4*)(Kbase + (size_t)(_k0 + kr) * 768 + kh);        \
            kb = *(const uint4*)(Kbase + (size_t)(_k0 + kr) * 768 + kh + 8);    \
            va = *(const uint4*)(Vbase + (size_t)vd * LL + _k0 + vs0);          \
            vb = *(const uint4*)(Vbase + (size_t)vd * LL + _k0 + 64 + vs0);     \
            kmg = (tid < 128) ? kmbase[_k0 + tid] : 0.0f;                       \
        } while (0)
    #define WRITEBUF(buf)                                                       \
        do {                                                                    \
            *(uint4*)(Ks[(buf)] + kr * 40 + kh) = ka;                           \
            *(uint4*)(Ks[(buf)] + kr * 40 + kh + 8) = kb;                       \
            *(uint4*)(Vs[(buf)] + vd * 136 + vs0) = va;                         \
            *(uint4*)(Vs[(buf)] + vd * 136 + 64 + vs0) = vb;                    \
            if (tid < 128) Kms[(buf)][tid] = kmg;                               \
        } while (0)

    LOADC(0);
    WRITEBUF(0);
    LOADC(1);

    bf16_t* Pw = Ps[wave];
    for (int c = 0; c < 8; ++c) {
        __syncthreads();
        int cur = c & 1;
        if (c + 1 < 8) WRITEBUF(cur ^ 1);
        if (c + 2 < 8) LOADC(c + 2);

        int k0 = c * 128;
        const bf16_t* Kc = Ks[cur];
        const bf16_t* Vc = Vs[cur];
        const float* kmc = Kms[cur];

        v4f sf[8];
        #pragma unroll
        for (int nt = 0; nt < 8; ++nt) {
            bf16x8 kf = *(const bf16x8*)(Kc + (nt * 16 + l16) * 40 + quad * 8);
            v4f zf = (v4f){0.f, 0.f, 0.f, 0.f};
            sf[nt] = __builtin_amdgcn_mfma_f32_16x16x32_bf16(kf, qf, zf, 0, 0, 0);
        }

        #pragma unroll
        for (int nt = 0; nt < 8; ++nt) {
            int kbase_nt = k0 + nt * 16 + quad * 4;
            float4 kmv = *(const float4*)(kmc + nt * 16 + quad * 4);
            float pv[4];
            #pragma unroll
            for (int reg = 0; reg < 4; ++reg) {
                float km = (reg == 0) ? kmv.x : (reg == 1) ? kmv.y : (reg == 2) ? kmv.z : kmv.w;
                float v = sf[nt][reg] * scale + km;
                if (mq && (qg != kbase_nt + reg)) v += NEGV;
                float p = __expf(v);
                lrun += p;
                pv[reg] = p;
            }
            bf16x4 pp = {(bf16_t)pv[0], (bf16_t)pv[1], (bf16_t)pv[2], (bf16_t)pv[3]};
            *(bf16x4*)(Pw + l16 * 136 + nt * 16 + quad * 4) = pp;
        }

        #pragma unroll
        for (int kt = 0; kt < 4; ++kt) {
            bf16x8 pf = *(const bf16x8*)(Pw + l16 * 136 + kt * 32 + quad * 8);
            #pragma unroll
            for (int nt2 = 0; nt2 < 2; ++nt2) {
                bf16x8 vf = *(const bf16x8*)(Vc + (nt2 * 16 + l16) * 136 + kt * 32 + quad * 8);
                oacc[nt2] = __builtin_amdgcn_mfma_f32_16x16x32_bf16(pf, vf, oacc[nt2], 0, 0, 0);
            }
        }
    }
    #undef LOADC
    #undef WRITEBUF

    lrun += __shfl_xor(lrun, 16);
    lrun += __shfl_xor(lrun, 32);
    float lq[4];
    #pragma unroll
    for (int reg = 0; reg < 4; ++reg) lq[reg] = __shfl(lrun, quad * 4 + reg);

    #pragma unroll
    for (int nt2 = 0; nt2 < 2; ++nt2)
        #pragma unroll
        for (int reg = 0; reg < 4; ++reg) {
            size_t row = (size_t)(b * LL) + q0 + quad * 4 + reg;
            Ob[row * 256 + h * DH + nt2 * 16 + l16] = (bf16_t)(oacc[nt2][reg] / lq[reg]);
        }
}

// ---------------------------------------------------------------------------
// LayerNorm (R1 verified, unchanged).
// ---------------------------------------------------------------------------
__global__ __launch_bounds__(256) void ln_kernel(
    const bf16_t* __restrict__ tmps, const float* __restrict__ w,
    const float* __restrict__ b, bf16_t* __restrict__ zb) {
    int wave = threadIdx.x >> 6, lane = threadIdx.x & 63;
    int row = blockIdx.x * 4 + wave;
    bf16x4 xb = *(const bf16x4*)(tmps + (size_t)row * D_MODEL + lane * 4);
    float x0 = (float)xb[0], x1 = (float)xb[1], x2 = (float)xb[2], x3 = (float)xb[3];
    float s = x0 + x1 + x2 + x3;
    #pragma unroll
    for (int off = 32; off > 0; off >>= 1) s += __shfl_xor(s, off);
    float mean = s * (1.0f / D_MODEL);
    float dx0 = x0 - mean, dx1 = x1 - mean, dx2 = x2 - mean, dx3 = x3 - mean;
    float sq = dx0 * dx0 + dx1 * dx1 + dx2 * dx2 + dx3 * dx3;
    #pragma unroll
    for (int off = 32; off > 0; off >>= 1) sq += __shfl_xor(sq, off);
    float inv = 1.0f / sqrtf(sq * (1.0f / D_MODEL) + 1e-5f);
    float4 wv = ((const float4*)w)[lane];
    float4 bv = ((const float4*)b)[lane];
    bf16x4 rb = {(bf16_t)(dx0 * inv * wv.x + bv.x),
                 (bf16_t)(dx1 * inv * wv.y + bv.y),
                 (bf16_t)(dx2 * inv * wv.z + bv.z),
                 (bf16_t)(dx3 * inv * wv.w + bv.w)};
    *(bf16x4*)(zb + (size_t)row * D_MODEL + lane * 4) = rb;
}

// ---------------------------------------------------------------------------
// Head stage 1 (R1 verified, unchanged).
// ---------------------------------------------------------------------------
__global__ __launch_bounds__(256) void head_h_kernel(
    const bf16_t* __restrict__ zb, const bf16_t* __restrict__ W1b,
    const float* __restrict__ mean_b1, const float* __restrict__ lv_b1,
    bf16_t* __restrict__ hb) {
    __shared__ __align__(16) bf16_t Xs[2][64 * 32 * 2];
    __shared__ __align__(16) bf16_t Ws[2][64 * 32 * 2];
    int tid = threadIdx.x;
    int wave = tid >> 6, lane = tid & 63;
    int quad = lane >> 4, l16 = lane & 15;
    int head = blockIdx.y;
    int n0 = blockIdx.x * 64;
    const bf16_t* W1h = W1b + (size_t)head * DFF * D_MODEL;
    const float* B1f = head ? lv_b1 : mean_b1;
    bf16_t* hbh = hb + (size_t)head * 64 * DFF;

    v4f acc[4];
    #pragma unroll
    for (int j = 0; j < 4; ++j) acc[j] = (v4f){0.f, 0.f, 0.f, 0.f};

    int sr = tid >> 3, ss = tid & 7;
    int gc = (ss ^ (sr & 7)) * 8;

#define HSTAGE(bufi, k0)                                                          \
    do {                                                                          \
        _Pragma("unroll")                                                         \
        for (int p = 0; p < 2; ++p) {                                             \
            int r = sr + p * 32;                                                  \
            const bf16_t* xr = zb + (size_t)((r >> 4) * LL + (TT - 1) * PP + (r & 15)) * D_MODEL; \
            gld16(Xs[bufi] + r * 64 + ss * 8, xr + (k0) + gc);                    \
            gld16(Ws[bufi] + r * 64 + ss * 8, W1h + (size_t)(n0 + r) * D_MODEL + (k0) + gc); \
        }                                                                         \
    } while (0)

    HSTAGE(0, 0);
    __syncthreads();
    const int T = D_MODEL / 64;   // 4
    int swl = l16 & 7;
    for (int t = 0; t < T; ++t) {
        int buf = t & 1;
        if (t + 1 < T) HSTAGE(buf ^ 1, (t + 1) * 64);
        const bf16_t* Xc = Xs[buf];
        const bf16_t* Wc = Ws[buf];
        int ra = wave * 16 + l16;
        #pragma unroll
        for (int h = 0; h < 2; ++h) {
            int g8 = ((h * 4 + quad) ^ swl) * 8;
            bf16x8 af = *(const bf16x8*)(Xc + ra * 64 + g8);
            #pragma unroll
            for (int nt = 0; nt < 4; ++nt) {
                bf16x8 bfr = *(const bf16x8*)(Wc + (nt * 16 + l16) * 64 + g8);
                acc[nt] = __builtin_amdgcn_mfma_f32_16x16x32_bf16(af, bfr, acc[nt], 0, 0, 0);
            }
        }
        __syncthreads();
    }
#undef HSTAGE

    #pragma unroll
    for (int nt = 0; nt < 4; ++nt) {
        int col = n0 + nt * 16 + l16;
        float bv = B1f[col];
        #pragma unroll
        for (int reg = 0; reg < 4; ++reg) {
            int row = wave * 16 + quad * 4 + reg;
            hbh[(size_t)row * DFF + col] = (bf16_t)fmaxf(acc[nt][reg] + bv, 0.0f);
        }
    }
}

// ---------------------------------------------------------------------------
// Head stage 2 (R1 verified, unchanged).
// ---------------------------------------------------------------------------
__global__ __launch_bounds__(256) void head_out_kernel(
    const bf16_t* __restrict__ hb, const bf16_t* __restrict__ W2b,
    const float* __restrict__ mean_b2, const float* __restrict__ lv_b2,
    float* __restrict__ out) {
    __shared__ __align__(16) bf16_t hrow[DFF];
    int tid = threadIdx.x;
    int bid = blockIdx.x;
    int head = bid >> 7, rr = (bid >> 1) & 63, half = bid & 1;
    int b = rr >> 4, p = rr & 15;

    if (tid < 128)
        *(uint4*)(hrow + tid * 8) =
            *(const uint4*)(hb + ((size_t)head * 64 + rr) * DFF + tid * 8);
    __syncthreads();

    int ol = tid >> 2, quarter = tid & 3;
    int o = half * 64 + ol;
    const bf16_t* wrow = W2b + ((size_t)head * DATA_DIM + o) * DFF + quarter * 256;
    const bf16_t* hseg = hrow + quarter * 256;
    float acc = 0.0f;
    #pragma unroll 8
    for (int j = 0; j < 32; ++j) {
        bf16x8 w = *(const bf16x8*)(wrow + j * 8);
        bf16x8 hv = *(const bf16x8*)(hseg + j * 8);
        #pragma unroll
        for (int e = 0; e < 8; ++e) acc += (float)w[e] * (float)hv[e];
    }
    acc += __shfl_xor(acc, 1);
    acc += __shfl_xor(acc, 2);
    if (quarter == 0) {
        const float* B2 = head ? lv_b2 : mean_b2;
        float hi = head ? 5.0f : 10.0f;
        float v = fminf(fmaxf(acc + B2[o], -10.0f), hi);
        int c = o >> 6;
        int pr = (o >> 3) & 7, pc = o & 7;
        int hh = (p >> 2) * 8 + pr, ww = (p & 3) * 8 + pc;
        out[(size_t)head * 8192 + ((size_t)(b * CC + c)) * 1024 + hh * 32 + ww] = v;
    }
}

// ---------------------------------------------------------------------------
extern "C" void kernel_launch(void* const* d_in, const int* in_sizes, int n_in,
                              void* d_out, int out_size, void* d_ws, size_t ws_size,
                              hipStream_t stream) {
    const float* img        = (const float*)d_in[0];
    const float* acq        = (const float*)d_in[1];
    const float* nan_token  = (const float*)d_in[2];
    const float* pad_embed  = (const float*)d_in[3];
    const float* emb_w      = (const float*)d_in[4];
    const float* emb_b      = (const float*)d_in[5];
    const float* spatial    = (const float*)d_in[6];
    const float* t_w1       = (const float*)d_in[7];
    const float* t_b1       = (const float*)d_in[8];
    const float* t_w2       = (const float*)d_in[9];
    const float* t_b2       = (const float*)d_in[10];
    const float* t_w3       = (const float*)d_in[11];
    const float* t_b3       = (const float*)d_in[12];
    const float* in_proj_w  = (const float*)d_in[13];
    const float* in_proj_b  = (const float*)d_in[14];
    const float* out_proj_w = (const float*)d_in[15];
    const float* out_proj_b = (const float*)d_in[16];
    const float* lin1_w     = (const float*)d_in[17];
    const float* lin1_b     = (const float*)d_in[18];
    const float* lin2_w     = (const float*)d_in[19];
    const float* lin2_b     = (const float*)d_in[20];
    const float* norm1_w    = (const float*)d_in[21];
    const float* norm1_b    = (const float*)d_in[22];
    const float* norm2_w    = (const float*)d_in[23];
    const float* norm2_b    = (const float*)d_in[24];
    const float* mean_w1    = (const float*)d_in[25];
    const float* mean_b1    = (const float*)d_in[26];
    const float* mean_w2    = (const float*)d_in[27];
    const float* mean_b2    = (const float*)d_in[28];
    const float* lv_w1      = (const float*)d_in[29];
    const float* lv_b1      = (const float*)d_in[30];
    const float* lv_w2      = (const float*)d_in[31];
    const float* lv_b2      = (const float*)d_in[32];

    const int M = BB * LL;   // 4096 tokens

    // ---- workspace carve-up ----
    char* wsb = (char*)d_ws;
    float* temb    = (float*)wsb;                    wsb += (size_t)BB * TT * D_MODEL * 4;
    float* kmaskf  = (float*)wsb;                    wsb += M * 4;
    int* framepad  = (int*)wsb;                      wsb += BB * TT * 4;
    int* masked    = (int*)wsb;                      wsb += M * 4;
    wsb = (char*)(((uintptr_t)wsb + 255) & ~(uintptr_t)255);
    bf16_t* zb     = (bf16_t*)wsb;                   wsb += (size_t)M * D_MODEL * 2;
    bf16_t* tmps   = (bf16_t*)wsb;                   wsb += (size_t)M * D_MODEL * 2;
    bf16_t* xpb    = (bf16_t*)wsb;                   wsb += (size_t)M * DATA_DIM * 2;
    bf16_t* qkvb   = (bf16_t*)wsb;                   wsb += (size_t)M * 768 * 2;
    bf16_t* VtG    = (bf16_t*)wsb;                   wsb += (size_t)M * D_MODEL * 2;
    bf16_t* attnb  = (bf16_t*)wsb;                   wsb += (size_t)M * D_MODEL * 2;
    bf16_t* ff1b   = (bf16_t*)wsb;                   wsb += (size_t)M * DFF * 2;
    bf16_t* inb    = (bf16_t*)wsb;                   wsb += (size_t)NLAYERS * 768 * D_MODEL * 2;
    bf16_t* outb   = (bf16_t*)wsb;                   wsb += (size_t)NLAYERS * D_MODEL * D_MODEL * 2;
    bf16_t* l1b    = (bf16_t*)wsb;                   wsb += (size_t)NLAYERS * DFF * D_MODEL * 2;
    bf16_t* l2b    = (bf16_t*)wsb;                   wsb += (size_t)NLAYERS * D_MODEL * DFF * 2;
    bf16_t* embwb  = (bf16_t*)wsb;                   wsb += (size_t)D_MODEL * DATA_DIM * 2;
    bf16_t* w1b    = (bf16_t*)wsb;                   wsb += (size_t)2 * DFF * D_MODEL * 2;
    bf16_t* w2b    = (bf16_t*)wsb;                   wsb += (size_t)2 * DATA_DIM * DFF * 2;
    bf16_t* hb     = (bf16_t*)wsb;                   wsb += (size_t)2 * 64 * DFF * 2;

    float* outF = (float*)d_out;

    // ---- merged weight conversion + prep (1 dispatch) ----
    {
        int tot = NLAYERS * 768 * D_MODEL + NLAYERS * D_MODEL * D_MODEL +
                  NLAYERS * DFF * D_MODEL + NLAYERS * D_MODEL * DFF +
                  D_MODEL * DATA_DIM + 2 * DFF * D_MODEL + 2 * DATA_DIM * DFF;
        f2b_prep_kernel<<<(tot / 4 + 255) / 256, 256, 0, stream>>>(
            in_proj_w, inb, out_proj_w, outb, lin1_w, l1b, lin2_w, l2b,
            emb_w, embwb, mean_w1, lv_w1, w1b, mean_w2, lv_w2, w2b,
            img, acq, t_w1, t_b1, t_w2, t_b2, t_w3, t_b3, temb, framepad);
    }

    patchify_kernel<<<M / 2, 256, 0, stream>>>(img, nan_token, framepad, xpb, masked, kmaskf);
    embed_gemm<<<dim3(D_MODEL / 64, M / 128), 256, 0, stream>>>(
        xpb, embwb, emb_b, spatial, temb, pad_embed, framepad, zb);

    // ---- transformer layers (bf16 residual stream) ----
    for (int l = 0; l < NLAYERS; ++l) {
        gemm_mfma<2, 0><<<dim3(768 / 64, M / 128), 256, 0, stream>>>(
            zb, inb + (size_t)l * 768 * D_MODEL, in_proj_b + (size_t)l * 768,
            qkvb, VtG, M, 768, D_MODEL);
        attn_mfma<<<BB * NHEAD * (LL / 64), 256, 0, stream>>>(qkvb, VtG, masked, kmaskf, attnb);
        // out_proj + residual -> tmps (bf16)
        gemm_small<<<dim3(D_MODEL / 64, M / 64), 256, 0, stream>>>(
            attnb, outb + (size_t)l * D_MODEL * D_MODEL, out_proj_b + (size_t)l * D_MODEL,
            zb, tmps, M, D_MODEL, D_MODEL);
        ln_kernel<<<M / 4, 256, 0, stream>>>(tmps, norm1_w + l * D_MODEL,
                                             norm1_b + l * D_MODEL, zb);
        gemm_mfma<1, 1><<<dim3(DFF / 64, M / 128), 256, 0, stream>>>(
            zb, l1b + (size_t)l * DFF * D_MODEL, lin1_b + (size_t)l * DFF,
            ff1b, nullptr, M, DFF, D_MODEL);
        // ff2 + residual -> tmps (bf16)
        gemm_small<<<dim3(D_MODEL / 64, M / 64), 256, 0, stream>>>(
            ff1b, l2b + (size_t)l * D_MODEL * DFF, lin2_b + (size_t)l * D_MODEL,
            zb, tmps, M, D_MODEL, DFF);
        ln_kernel<<<M / 4, 256, 0, stream>>>(tmps, norm2_w + l * D_MODEL,
                                             norm2_b + l * D_MODEL, zb);
    }

    // ---- heads ----
    head_h_kernel<<<dim3(DFF / 64, 2), 256, 0, stream>>>(zb, w1b, mean_b1, lv_b1, hb);
    head_out_kernel<<<256, 256, 0, stream>>>(hb, w2b, mean_b2, lv_b2, outF);
}